// Round 1
// baseline (20.339 us; speedup 1.0000x reference)
//
#include <hip/hip_runtime.h>
#include <math.h>

// Problem constants (from reference): B=128, L=4096, FILTER=2, OL=4095, 10 classes.
#define BATCH 128
#define LEN   4096
#define OL    4095
#define NC    10

// Closed form derived from the quantum circuit:
//   feats[k,b,i] = Ck * cos(x[b,i,1]) * cos(x[b,i+1,0]) * cos(x[b,i+1,1])
//   Ck = cos(p[k,1]) * cos(p[k,2]) * cos(p[k,3])
//   logits[b,c] = sum_i g[b,i] * (C0*W[2i,c] + C1*W[2i+1,c]) + bias[c]
//   out = softmax(logits)
__global__ __launch_bounds__(256) void qcnn_fused(
    const float* __restrict__ inputs,   // (B, L, 2)
    const float* __restrict__ params,   // (2, 1, 4) flat
    const float* __restrict__ W,        // (OL*2, 10)
    const float* __restrict__ bias,     // (10,)
    float* __restrict__ out)            // (B, 10)
{
    const int b   = blockIdx.x;
    const int tid = threadIdx.x;

    // Per-thread redundant scalar compute (cheap, avoids extra kernel).
    const float C0 = cosf(params[1]) * cosf(params[2]) * cosf(params[3]);
    const float C1 = cosf(params[5]) * cosf(params[6]) * cosf(params[7]);

    const float* __restrict__ xrow = inputs + (size_t)b * (LEN * 2);

    float acc[NC];
#pragma unroll
    for (int c = 0; c < NC; ++c) acc[c] = 0.0f;

    for (int i = tid; i < OL; i += 256) {
        // window i uses x[i,1], x[i+1,0], x[i+1,1] -> flat offsets 2i+1, 2i+2, 2i+3
        const float g = cosf(xrow[2 * i + 1]) * cosf(xrow[2 * i + 2]) * cosf(xrow[2 * i + 3]);
        const float* __restrict__ w0 = W + (size_t)i * 20;  // rows 2i and 2i+1 are contiguous
#pragma unroll
        for (int c = 0; c < NC; ++c) {
            const float v = fmaf(C1, w0[c + 10], C0 * w0[c]);
            acc[c] = fmaf(g, v, acc[c]);
        }
    }

    // Wave (64-lane) butterfly reduce each accumulator.
#pragma unroll
    for (int c = 0; c < NC; ++c) {
        float v = acc[c];
#pragma unroll
        for (int off = 32; off > 0; off >>= 1)
            v += __shfl_xor(v, off, 64);
        acc[c] = v;
    }

    __shared__ float red[4][NC];
    const int lane = tid & 63;
    const int wave = tid >> 6;
    if (lane == 0) {
#pragma unroll
        for (int c = 0; c < NC; ++c) red[wave][c] = acc[c];
    }
    __syncthreads();

    if (tid == 0) {
        float logits[NC];
        float m = -1e30f;
#pragma unroll
        for (int c = 0; c < NC; ++c) {
            const float v = red[0][c] + red[1][c] + red[2][c] + red[3][c] + bias[c];
            logits[c] = v;
            m = fmaxf(m, v);
        }
        float s = 0.0f;
#pragma unroll
        for (int c = 0; c < NC; ++c) {
            logits[c] = expf(logits[c] - m);
            s += logits[c];
        }
        const float inv = 1.0f / s;
#pragma unroll
        for (int c = 0; c < NC; ++c) out[b * NC + c] = logits[c] * inv;
    }
}

extern "C" void kernel_launch(void* const* d_in, const int* in_sizes, int n_in,
                              void* d_out, int out_size, void* d_ws, size_t ws_size,
                              hipStream_t stream) {
    const float* inputs = (const float*)d_in[0];  // (128, 4096, 2) f32
    const float* params = (const float*)d_in[1];  // (2, 1, 4) f32
    const float* W      = (const float*)d_in[2];  // (8190, 10) f32
    const float* bias   = (const float*)d_in[3];  // (10,) f32
    float* out          = (float*)d_out;          // (128, 10) f32

    qcnn_fused<<<BATCH, 256, 0, stream>>>(inputs, params, W, bias, out);
}

// Round 2
// 13.448 us; speedup vs baseline: 1.5124x; 1.5124x over previous
//
#include <hip/hip_runtime.h>
#include <math.h>

// Problem constants: B=128, L=4096, FILTER=2, OL=4095, 10 classes.
#define BATCH 128
#define LEN   4096
#define OL    4095
#define NC    10
#define WPB   512                 // windows per block
#define BPB   8                   // blocks per batch = ceil(OL/WPB)
#define WPT   (WPB / 256)         // windows per thread = 2

// Closed form (derived R0, verified absmax 0.0):
//   g[b,i] = cos(x[b,i,1]) * cos(x[b,i+1,0]) * cos(x[b,i+1,1])
//   Ck = cos(p[k,1]) * cos(p[k,2]) * cos(p[k,3])
//   logits[b,c] = sum_i g[b,i] * (C0*W[2i,c] + C1*W[2i+1,c]) + bias[c]
//   out = softmax(logits)

// Kernel 1: partial logits per (batch, i-chunk) -> ws[block][10]
__global__ __launch_bounds__(256) void qcnn_partial(
    const float* __restrict__ inputs,   // (B, L, 2)
    const float* __restrict__ params,   // (2, 1, 4) flat
    const float* __restrict__ W,        // (OL*2, 10)
    float* __restrict__ ws)             // (B*BPB, 10) partials
{
    const int blk   = blockIdx.x;
    const int b     = blk / BPB;        // batch
    const int chunk = blk % BPB;        // i-chunk within batch
    const int tid   = threadIdx.x;

    const float C0 = cosf(params[1]) * cosf(params[2]) * cosf(params[3]);
    const float C1 = cosf(params[5]) * cosf(params[6]) * cosf(params[7]);

    const float* __restrict__ xrow = inputs + (size_t)b * (LEN * 2);

    float acc[NC];
#pragma unroll
    for (int c = 0; c < NC; ++c) acc[c] = 0.0f;

#pragma unroll
    for (int k = 0; k < WPT; ++k) {
        const int i = chunk * WPB + k * 256 + tid;
        if (i < OL) {
            // window i uses flat offsets 2i+1, 2i+2, 2i+3
            const float g = cosf(xrow[2 * i + 1]) * cosf(xrow[2 * i + 2]) * cosf(xrow[2 * i + 3]);
            const float* __restrict__ w0 = W + (size_t)i * 20;  // rows 2i, 2i+1 contiguous
#pragma unroll
            for (int c = 0; c < NC; ++c) {
                const float v = fmaf(C1, w0[c + 10], C0 * w0[c]);
                acc[c] = fmaf(g, v, acc[c]);
            }
        }
    }

    // Wave butterfly reduce each of the 10 accumulators.
#pragma unroll
    for (int c = 0; c < NC; ++c) {
        float v = acc[c];
#pragma unroll
        for (int off = 32; off > 0; off >>= 1)
            v += __shfl_xor(v, off, 64);
        acc[c] = v;
    }

    __shared__ float red[4][NC];
    const int lane = tid & 63;
    const int wave = tid >> 6;
    if (lane == 0) {
#pragma unroll
        for (int c = 0; c < NC; ++c) red[wave][c] = acc[c];
    }
    __syncthreads();

    if (tid < NC)
        ws[(size_t)blk * NC + tid] = red[0][tid] + red[1][tid] + red[2][tid] + red[3][tid];
}

// Kernel 2: reduce BPB partials per batch, add bias, softmax.
__global__ __launch_bounds__(128) void qcnn_softmax(
    const float* __restrict__ ws,       // (B*BPB, 10)
    const float* __restrict__ bias,     // (10,)
    float* __restrict__ out)            // (B, 10)
{
    const int b = threadIdx.x;          // one thread per batch row
    float logits[NC];
#pragma unroll
    for (int c = 0; c < NC; ++c) logits[c] = bias[c];
    const float* __restrict__ p = ws + (size_t)b * BPB * NC;
#pragma unroll
    for (int k = 0; k < BPB; ++k)
#pragma unroll
        for (int c = 0; c < NC; ++c) logits[c] += p[k * NC + c];

    float m = -1e30f;
#pragma unroll
    for (int c = 0; c < NC; ++c) m = fmaxf(m, logits[c]);
    float s = 0.0f;
#pragma unroll
    for (int c = 0; c < NC; ++c) { logits[c] = expf(logits[c] - m); s += logits[c]; }
    const float inv = 1.0f / s;
#pragma unroll
    for (int c = 0; c < NC; ++c) out[b * NC + c] = logits[c] * inv;
}

extern "C" void kernel_launch(void* const* d_in, const int* in_sizes, int n_in,
                              void* d_out, int out_size, void* d_ws, size_t ws_size,
                              hipStream_t stream) {
    const float* inputs = (const float*)d_in[0];  // (128, 4096, 2) f32
    const float* params = (const float*)d_in[1];  // (2, 1, 4) f32
    const float* W      = (const float*)d_in[2];  // (8190, 10) f32
    const float* bias   = (const float*)d_in[3];  // (10,) f32
    float* out          = (float*)d_out;          // (128, 10) f32
    float* ws           = (float*)d_ws;           // BATCH*BPB*NC floats (40 KB)

    qcnn_partial<<<BATCH * BPB, 256, 0, stream>>>(inputs, params, W, ws);
    qcnn_softmax<<<1, 128, 0, stream>>>(ws, bias, out);
}

// Round 3
// 12.383 us; speedup vs baseline: 1.6424x; 1.0860x over previous
//
#include <hip/hip_runtime.h>
#include <math.h>

// Problem constants: B=128, L=4096, FILTER=2, OL=4095, 10 classes.
#define BATCH 128
#define LEN   4096
#define OL    4095
#define NC    10
#define TPB   1024
#define WPT   4    // ceil(OL / TPB)

// Closed form (derived R0, verified absmax 0.0):
//   g[b,i] = cos(x[b,i,1]) * cos(x[b,i+1,0]) * cos(x[b,i+1,1])
//   Ck = cos(p[k,1]) * cos(p[k,2]) * cos(p[k,3])
//   logits[b,c] = sum_i g[b,i] * (C0*W[2i,c] + C1*W[2i+1,c]) + bias[c]
//   out = softmax(logits)
//
// Single kernel: one block per batch, 16 waves, in-block reduce + softmax.
__global__ __launch_bounds__(TPB) void qcnn_fused(
    const float* __restrict__ inputs,   // (B, L, 2)
    const float* __restrict__ params,   // (2, 1, 4) flat
    const float* __restrict__ W,        // (OL*2, 10), rows 2i/2i+1 contiguous (80 B, 16B-aligned)
    const float* __restrict__ bias,     // (10,)
    float* __restrict__ out)            // (B, 10)
{
    const int b   = blockIdx.x;
    const int tid = threadIdx.x;

    const float* __restrict__ xrow = inputs + (size_t)b * (LEN * 2);

    float acc0[NC], acc1[NC];
#pragma unroll
    for (int c = 0; c < NC; ++c) { acc0[c] = 0.0f; acc1[c] = 0.0f; }

#pragma unroll
    for (int w = 0; w < WPT; ++w) {
        const int i = w * TPB + tid;
        if (i < OL) {
            // window i needs x[2i+1], x[2i+2], x[2i+3]; 8B-aligned float2 pair
            const float2 xa = *(const float2*)(xrow + 2 * i);      // x[2i], x[2i+1]
            const float2 xb = *(const float2*)(xrow + 2 * i + 2);  // x[2i+2], x[2i+3]
            const float g = cosf(xa.y) * cosf(xb.x) * cosf(xb.y);

            const float4* __restrict__ wv = (const float4*)(W + (size_t)i * 20);
            const float4 q0 = wv[0], q1 = wv[1], q2 = wv[2], q3 = wv[3], q4 = wv[4];
            // q0..q1,q2.xy = W[2i,0..9]; q2.zw,q3,q4 = W[2i+1,0..9]
            acc0[0] = fmaf(g, q0.x, acc0[0]);  acc0[1] = fmaf(g, q0.y, acc0[1]);
            acc0[2] = fmaf(g, q0.z, acc0[2]);  acc0[3] = fmaf(g, q0.w, acc0[3]);
            acc0[4] = fmaf(g, q1.x, acc0[4]);  acc0[5] = fmaf(g, q1.y, acc0[5]);
            acc0[6] = fmaf(g, q1.z, acc0[6]);  acc0[7] = fmaf(g, q1.w, acc0[7]);
            acc0[8] = fmaf(g, q2.x, acc0[8]);  acc0[9] = fmaf(g, q2.y, acc0[9]);
            acc1[0] = fmaf(g, q2.z, acc1[0]);  acc1[1] = fmaf(g, q2.w, acc1[1]);
            acc1[2] = fmaf(g, q3.x, acc1[2]);  acc1[3] = fmaf(g, q3.y, acc1[3]);
            acc1[4] = fmaf(g, q3.z, acc1[4]);  acc1[5] = fmaf(g, q3.w, acc1[5]);
            acc1[6] = fmaf(g, q4.x, acc1[6]);  acc1[7] = fmaf(g, q4.y, acc1[7]);
            acc1[8] = fmaf(g, q4.z, acc1[8]);  acc1[9] = fmaf(g, q4.w, acc1[9]);
        }
    }

    // Fold the two weight rows with the uniform circuit constants (once, pre-reduce).
    const float C0 = cosf(params[1]) * cosf(params[2]) * cosf(params[3]);
    const float C1 = cosf(params[5]) * cosf(params[6]) * cosf(params[7]);
    float accC[NC];
#pragma unroll
    for (int c = 0; c < NC; ++c) accC[c] = fmaf(C1, acc1[c], C0 * acc0[c]);

    // Wave butterfly reduce.
#pragma unroll
    for (int c = 0; c < NC; ++c) {
        float v = accC[c];
#pragma unroll
        for (int off = 32; off > 0; off >>= 1)
            v += __shfl_xor(v, off, 64);
        accC[c] = v;
    }

    __shared__ float red[TPB / 64][NC];
    const int lane = tid & 63;
    const int wave = tid >> 6;
    if (lane == 0) {
#pragma unroll
        for (int c = 0; c < NC; ++c) red[wave][c] = accC[c];
    }
    __syncthreads();

    __shared__ float logits_s[NC];
    if (tid < NC) {
        float v = bias[tid];
#pragma unroll
        for (int k = 0; k < TPB / 64; ++k) v += red[k][tid];
        logits_s[tid] = v;
    }
    __syncthreads();

    if (tid == 0) {
        float logits[NC];
        float m = -1e30f;
#pragma unroll
        for (int c = 0; c < NC; ++c) { logits[c] = logits_s[c]; m = fmaxf(m, logits[c]); }
        float s = 0.0f;
#pragma unroll
        for (int c = 0; c < NC; ++c) { logits[c] = expf(logits[c] - m); s += logits[c]; }
        const float inv = 1.0f / s;
#pragma unroll
        for (int c = 0; c < NC; ++c) out[b * NC + c] = logits[c] * inv;
    }
}

extern "C" void kernel_launch(void* const* d_in, const int* in_sizes, int n_in,
                              void* d_out, int out_size, void* d_ws, size_t ws_size,
                              hipStream_t stream) {
    const float* inputs = (const float*)d_in[0];  // (128, 4096, 2) f32
    const float* params = (const float*)d_in[1];  // (2, 1, 4) f32
    const float* W      = (const float*)d_in[2];  // (8190, 10) f32
    const float* bias   = (const float*)d_in[3];  // (10,) f32
    float* out          = (float*)d_out;          // (128, 10) f32

    qcnn_fused<<<BATCH, TPB, 0, stream>>>(inputs, params, W, bias, out);
}

// Round 4
// 12.374 us; speedup vs baseline: 1.6436x; 1.0007x over previous
//
#include <hip/hip_runtime.h>
#include <math.h>

// Problem constants: B=128, L=4096, FILTER=2, OL=4095, 10 classes.
#define BATCH 128
#define LEN   4096
#define OL    4095
#define NC    10
#define TPB   1024
#define NPAIR 2048   // window pairs (2j, 2j+1), j in [0, 2048); j=2047 has only window 4094

// Closed form (derived R0, verified absmax 0.0):
//   g[b,i] = cos(x[b,i,1]) * cos(x[b,i+1,0]) * cos(x[b,i+1,1])
//   Ck = cos(p[k,1]) * cos(p[k,2]) * cos(p[k,3])
//   logits[b,c] = sum_i g[b,i] * (C0*W[2i,c] + C1*W[2i+1,c]) + bias[c]
//   out = softmax(logits)
//
// R4 change: __cosf/__expf (v_cos_f32/v_exp_f32 fast path) instead of libm
// cosf/expf; consecutive-window pairing shares one cos and vectorizes x loads.
__global__ __launch_bounds__(TPB) void qcnn_fused(
    const float* __restrict__ inputs,   // (B, L, 2)
    const float* __restrict__ params,   // (2, 1, 4) flat
    const float* __restrict__ W,        // (OL*2, 10)
    const float* __restrict__ bias,     // (10,)
    float* __restrict__ out)            // (B, 10)
{
    const int b   = blockIdx.x;
    const int tid = threadIdx.x;

    const float* __restrict__ xrow = inputs + (size_t)b * (LEN * 2);

    float acc0[NC], acc1[NC];
#pragma unroll
    for (int c = 0; c < NC; ++c) { acc0[c] = 0.0f; acc1[c] = 0.0f; }

#pragma unroll
    for (int k = 0; k < NPAIR / TPB; ++k) {
        const int j  = k * TPB + tid;       // pair index, windows i0=2j, i1=2j+1
        const int i0 = 2 * j;

        // x[4j..4j+3] (16B aligned) covers window i0; x[4j+4..4j+5] completes i1.
        const float4 X = *(const float4*)(xrow + 4 * j);
        const float cy = __cosf(X.y);
        const float cz = __cosf(X.z);
        const float cw = __cosf(X.w);
        const float g0 = cy * cz * cw;

        {   // window i0: W rows 2*i0, 2*i0+1 = 20 floats at W + 20*i0
            const float4* __restrict__ wv = (const float4*)(W + (size_t)i0 * 20);
            const float4 q0 = wv[0], q1 = wv[1], q2 = wv[2], q3 = wv[3], q4 = wv[4];
            acc0[0] = fmaf(g0, q0.x, acc0[0]);  acc0[1] = fmaf(g0, q0.y, acc0[1]);
            acc0[2] = fmaf(g0, q0.z, acc0[2]);  acc0[3] = fmaf(g0, q0.w, acc0[3]);
            acc0[4] = fmaf(g0, q1.x, acc0[4]);  acc0[5] = fmaf(g0, q1.y, acc0[5]);
            acc0[6] = fmaf(g0, q1.z, acc0[6]);  acc0[7] = fmaf(g0, q1.w, acc0[7]);
            acc0[8] = fmaf(g0, q2.x, acc0[8]);  acc0[9] = fmaf(g0, q2.y, acc0[9]);
            acc1[0] = fmaf(g0, q2.z, acc1[0]);  acc1[1] = fmaf(g0, q2.w, acc1[1]);
            acc1[2] = fmaf(g0, q3.x, acc1[2]);  acc1[3] = fmaf(g0, q3.y, acc1[3]);
            acc1[4] = fmaf(g0, q3.z, acc1[4]);  acc1[5] = fmaf(g0, q3.w, acc1[5]);
            acc1[6] = fmaf(g0, q4.x, acc1[6]);  acc1[7] = fmaf(g0, q4.y, acc1[7]);
            acc1[8] = fmaf(g0, q4.z, acc1[8]);  acc1[9] = fmaf(g0, q4.w, acc1[9]);
        }

        if (j < NPAIR - 1) {                 // window i1 = 2j+1 (skip only j=2047 -> i1=4095)
            const float2 Y = *(const float2*)(xrow + 4 * j + 4);
            const float g1 = cw * __cosf(Y.x) * __cosf(Y.y);
            const float4* __restrict__ wv = (const float4*)(W + (size_t)(i0 + 1) * 20);
            const float4 q0 = wv[0], q1 = wv[1], q2 = wv[2], q3 = wv[3], q4 = wv[4];
            acc0[0] = fmaf(g1, q0.x, acc0[0]);  acc0[1] = fmaf(g1, q0.y, acc0[1]);
            acc0[2] = fmaf(g1, q0.z, acc0[2]);  acc0[3] = fmaf(g1, q0.w, acc0[3]);
            acc0[4] = fmaf(g1, q1.x, acc0[4]);  acc0[5] = fmaf(g1, q1.y, acc0[5]);
            acc0[6] = fmaf(g1, q1.z, acc0[6]);  acc0[7] = fmaf(g1, q1.w, acc0[7]);
            acc0[8] = fmaf(g1, q2.x, acc0[8]);  acc0[9] = fmaf(g1, q2.y, acc0[9]);
            acc1[0] = fmaf(g1, q2.z, acc1[0]);  acc1[1] = fmaf(g1, q2.w, acc1[1]);
            acc1[2] = fmaf(g1, q3.x, acc1[2]);  acc1[3] = fmaf(g1, q3.y, acc1[3]);
            acc1[4] = fmaf(g1, q3.z, acc1[4]);  acc1[5] = fmaf(g1, q3.w, acc1[5]);
            acc1[6] = fmaf(g1, q4.x, acc1[6]);  acc1[7] = fmaf(g1, q4.y, acc1[7]);
            acc1[8] = fmaf(g1, q4.z, acc1[8]);  acc1[9] = fmaf(g1, q4.w, acc1[9]);
        }
    }

    // Fold the two weight-row accumulators with the uniform circuit constants.
    const float C0 = __cosf(params[1]) * __cosf(params[2]) * __cosf(params[3]);
    const float C1 = __cosf(params[5]) * __cosf(params[6]) * __cosf(params[7]);
    float accC[NC];
#pragma unroll
    for (int c = 0; c < NC; ++c) accC[c] = fmaf(C1, acc1[c], C0 * acc0[c]);

    // Wave butterfly reduce.
#pragma unroll
    for (int c = 0; c < NC; ++c) {
        float v = accC[c];
#pragma unroll
        for (int off = 32; off > 0; off >>= 1)
            v += __shfl_xor(v, off, 64);
        accC[c] = v;
    }

    __shared__ float red[TPB / 64][NC];
    const int lane = tid & 63;
    const int wave = tid >> 6;
    if (lane == 0) {
#pragma unroll
        for (int c = 0; c < NC; ++c) red[wave][c] = accC[c];
    }
    __syncthreads();

    __shared__ float logits_s[NC];
    if (tid < NC) {
        float v = bias[tid];
#pragma unroll
        for (int k = 0; k < TPB / 64; ++k) v += red[k][tid];
        logits_s[tid] = v;
    }
    __syncthreads();

    if (tid == 0) {
        float logits[NC];
        float m = -1e30f;
#pragma unroll
        for (int c = 0; c < NC; ++c) { logits[c] = logits_s[c]; m = fmaxf(m, logits[c]); }
        float s = 0.0f;
#pragma unroll
        for (int c = 0; c < NC; ++c) { logits[c] = __expf(logits[c] - m); s += logits[c]; }
        const float inv = 1.0f / s;
#pragma unroll
        for (int c = 0; c < NC; ++c) out[b * NC + c] = logits[c] * inv;
    }
}

extern "C" void kernel_launch(void* const* d_in, const int* in_sizes, int n_in,
                              void* d_out, int out_size, void* d_ws, size_t ws_size,
                              hipStream_t stream) {
    const float* inputs = (const float*)d_in[0];  // (128, 4096, 2) f32
    const float* params = (const float*)d_in[1];  // (2, 1, 4) f32
    const float* W      = (const float*)d_in[2];  // (8190, 10) f32
    const float* bias   = (const float*)d_in[3];  // (10,) f32
    float* out          = (float*)d_out;          // (128, 10) f32

    qcnn_fused<<<BATCH, TPB, 0, stream>>>(inputs, params, W, bias, out);
}